// Round 3
// baseline (114.904 us; speedup 1.0000x reference)
//
#include <hip/hip_runtime.h>
#include <hip/hip_bf16.h>

typedef _Float16 f16;
typedef _Float16 half8 __attribute__((ext_vector_type(8)));
typedef _Float16 half4 __attribute__((ext_vector_type(4)));
typedef float floatx4 __attribute__((ext_vector_type(4)));

#define BM 64

// ---- ws layout (f16 element offsets) ----
#define WA_OFF 0         // 65536 f16 : WaT frag order (CT=16,KT=8) — A-operand of swapped GEMM1
#define WB_OFF 65536     // 18432 f16 : WbT (CT=9, KT=4)  ct: 0-7=W2, 8=W12
#define WC_OFF 83968     // 2048 f16  : WcT (CT=1, KT=4)  rows 0-3 = W22 cols
#define WF2_OFF 86016    // 4096 f16  : Wf2T [4][CT=2,KT=1]
#define WSF_BYTE_OFF 180224
// wsf (float offsets)
#define BA_OFF 0      // 256: b1 | bf1
#define BB_OFF 256    // 144: b2 | b12
#define BCC_OFF 400   // 4  : b22
#define BF2_OFF 404   // 128: bf2
#define WFIN_OFF 532  // 32
#define BFIN_OFF 564  // 1

__global__ __launch_bounds__(256) void prep_kernel(
    const float* __restrict__ ctx, const float* __restrict__ W1,
    const float* __restrict__ b1, const float* __restrict__ W2,
    const float* __restrict__ b2, const float* __restrict__ W12,
    const float* __restrict__ b12, const float* __restrict__ W22,
    const float* __restrict__ b22, const float* __restrict__ Wf1,
    const float* __restrict__ bf1, const float* __restrict__ Wf2,
    const float* __restrict__ bf2, const float* __restrict__ Wfin,
    const float* __restrict__ bfin, f16* __restrict__ wsh,
    float* __restrict__ wsf)
{
  int tid = blockIdx.x * 256 + threadIdx.x;
  if (tid < 65536) {
    int j = tid & 7, l = (tid >> 3) & 63, kt = (tid >> 9) & 7, nt = tid >> 12;
    int k = kt * 32 + ((l >> 4) << 3) + j, n = nt * 16 + (l & 15);
    float v;
    if (n < 128) v = ctx[k] * W1[k * 128 + n];
    else { int c = n - 128; v = Wf1[((c >> 5) * 256 + k) * 32 + (c & 31)]; }
    wsh[tid] = (f16)v;
  } else if (tid < WB_OFF + 18432) {
    int o = tid - WB_OFF;
    int j = o & 7, l = (o >> 3) & 63, kt = (o >> 9) & 3, nt = o >> 11;
    int k = kt * 32 + ((l >> 4) << 3) + j, n = nt * 16 + (l & 15);
    float v = (n < 128) ? W2[k * 128 + n] : W12[k * 16 + (n - 128)];
    wsh[tid] = (f16)v;
  } else if (tid < WC_OFF + 2048) {
    int o = tid - WC_OFF;
    int j = o & 7, l = (o >> 3) & 63, kt = (o >> 9) & 3;
    int k = kt * 32 + ((l >> 4) << 3) + j, n = l & 15;
    float v = (n < 4) ? W22[k * 4 + n] : 0.f;
    wsh[tid] = (f16)v;
  } else if (tid < WF2_OFF + 4096) {
    int o = tid - WF2_OFF;
    int j = o & 7, l = (o >> 3) & 63, ent = o >> 9;
    int e = ent >> 1, nt = ent & 1;
    int k = ((l >> 4) << 3) + j, n = nt * 16 + (l & 15);
    wsh[tid] = (f16)Wf2[(e * 32 + k) * 32 + n];
  } else if (tid < 90112 + 565) {
    int o = tid - 90112;
    float v;
    if (o < 128) v = b1[o];
    else if (o < 256) v = bf1[o - 128];
    else if (o < 384) v = b2[o - 256];
    else if (o < 400) v = b12[o - 384];
    else if (o < 404) v = b22[o - 400];
    else if (o < 532) v = bf2[o - 404];
    else if (o < 564) v = Wfin[o - 532];
    else v = bfin[0];
    wsf[o] = v;
  }
}

#define MFMA16(A, Bv, C) __builtin_amdgcn_mfma_f32_16x16x32_f16(A, Bv, C, 0, 0, 0)

// LDS map (bytes), 35 KB total -> 4 blocks/CU:
//  G    0..32767   [64][512B] f16 swz :
//        phase A: x-tile ([64][256] f16)
//        phase B: h (bytes 0..255/row) | o1 (bytes 256..511/row)
//        phase C: h2 overlays h in place; in2 overlays o1 in place
//  L1   32768..34815 [64][16] f16 : logits1 ; overlaid by part [4][64] f32 in G4
//  C2   34816..35839 [64][4] f32
#define L1_OFF 32768
#define PART_OFF 32768
#define C2_OFF 34816

__global__ __launch_bounds__(256, 4) void fused_kernel(
    const float* __restrict__ x, const f16* __restrict__ wsh,
    const float* __restrict__ wsf, float* __restrict__ out)
{
  __shared__ __attribute__((aligned(16))) char lds[35840];
  const int t = threadIdx.x;
  const int lane = t & 63;
  const int w = t >> 6;
  const int l15 = lane & 15;
  const int l4 = lane >> 4;
  const size_t base = (size_t)blockIdx.x * BM;

  // ---- stage x tile -> G (f16, swizzled) ----
#pragma unroll
  for (int it = 0; it < 8; ++it) {
    int c = it * 256 + t;
    int r = c >> 5;
    int k0 = (c & 31) << 3;
    const float4* xv = (const float4*)(x + (base + (size_t)r) * 256 + k0);
    float4 a = xv[0], b = xv[1];
    half8 hv;
    hv[0] = (f16)a.x; hv[1] = (f16)a.y; hv[2] = (f16)a.z; hv[3] = (f16)a.w;
    hv[4] = (f16)b.x; hv[5] = (f16)b.y; hv[6] = (f16)b.z; hv[7] = (f16)b.w;
    int addr = (r * 512 + k0 * 2) ^ ((r & 7) << 4);
    *(half8*)(lds + addr) = hv;
  }
  __syncthreads();  // b0

  // ---- GEMM1 (swapped: A=WaT, B=x): h|o1 = relu(...), overlaying x ----
  {
    floatx4 acc[4][4];
#pragma unroll
    for (int q = 0; q < 4; ++q)
#pragma unroll
      for (int mt = 0; mt < 4; ++mt) acc[q][mt] = (floatx4){0.f, 0.f, 0.f, 0.f};
    for (int kt = 0; kt < 8; ++kt) {
      half8 Bx[4];
#pragma unroll
      for (int mt = 0; mt < 4; ++mt) {
        int r = mt * 16 + l15;
        int addr = (r * 512 + kt * 64 + (l4 << 4)) ^ ((r & 7) << 4);
        Bx[mt] = *(const half8*)(lds + addr);
      }
#pragma unroll
      for (int q = 0; q < 4; ++q) {
        half8 Wf = *(const half8*)(wsh + WA_OFF + (size_t)(((w * 4 + q) * 8 + kt) * 64 + lane) * 8);
#pragma unroll
        for (int mt = 0; mt < 4; ++mt) acc[q][mt] = MFMA16(Wf, Bx[mt], acc[q][mt]);
      }
    }
    __syncthreads();  // b1: all x reads done before overlay writes
#pragma unroll
    for (int q = 0; q < 4; ++q) {
      int c0 = (w * 4 + q) * 16 + l4 * 4;
      float4 bias = *(const float4*)(wsf + BA_OFF + c0);
#pragma unroll
      for (int mt = 0; mt < 4; ++mt) {
        int r = mt * 16 + l15;
        half4 hv;
#pragma unroll
        for (int i = 0; i < 4; ++i) hv[i] = (f16)fmaxf(acc[q][mt][i] + ((const float*)&bias)[i], 0.f);
        int addr = (r * 512 + c0 * 2) ^ ((r & 7) << 4);
        *(half4*)(lds + addr) = hv;
      }
    }
  }
  __syncthreads();  // b2

  // ---- GEMM2: h2 = relu(h @ W2) overlaying h; L1 = h @ W12 ----
  {
    floatx4 acc2[2][4];
    floatx4 accL[4];
#pragma unroll
    for (int qi = 0; qi < 2; ++qi)
#pragma unroll
      for (int mt = 0; mt < 4; ++mt) acc2[qi][mt] = (floatx4){0.f, 0.f, 0.f, 0.f};
#pragma unroll
    for (int mt = 0; mt < 4; ++mt) accL[mt] = (floatx4){0.f, 0.f, 0.f, 0.f};

    for (int kt = 0; kt < 4; ++kt) {
      half8 Bh[4];
#pragma unroll
      for (int mt = 0; mt < 4; ++mt) {
        int r = mt * 16 + l15;
        int addr = (r * 512 + kt * 64 + (l4 << 4)) ^ ((r & 7) << 4);
        Bh[mt] = *(const half8*)(lds + addr);
      }
#pragma unroll
      for (int qi = 0; qi < 2; ++qi) {
        half8 Wf = *(const half8*)(wsh + WB_OFF + (size_t)(((w + qi * 4) * 4 + kt) * 64 + lane) * 8);
#pragma unroll
        for (int mt = 0; mt < 4; ++mt) acc2[qi][mt] = MFMA16(Wf, Bh[mt], acc2[qi][mt]);
      }
      if (w == 3) {
        half8 Wf = *(const half8*)(wsh + WB_OFF + (size_t)((32 + kt) * 64 + lane) * 8);
#pragma unroll
        for (int mt = 0; mt < 4; ++mt) accL[mt] = MFMA16(Wf, Bh[mt], accL[mt]);
      }
    }
    __syncthreads();  // b3: all h reads done before in-place h2 overwrite
#pragma unroll
    for (int qi = 0; qi < 2; ++qi) {
      int c0 = (w + qi * 4) * 16 + l4 * 4;
      float4 bias = *(const float4*)(wsf + BB_OFF + c0);
#pragma unroll
      for (int mt = 0; mt < 4; ++mt) {
        int r = mt * 16 + l15;
        half4 hv;
#pragma unroll
        for (int i = 0; i < 4; ++i) hv[i] = (f16)fmaxf(acc2[qi][mt][i] + ((const float*)&bias)[i], 0.f);
        int addr = (r * 512 + c0 * 2) ^ ((r & 7) << 4);
        *(half4*)(lds + addr) = hv;
      }
    }
    if (w == 3) {
      int c0 = l4 * 4;
      float4 bias = *(const float4*)(wsf + BB_OFF + 128 + c0);
#pragma unroll
      for (int mt = 0; mt < 4; ++mt) {
        int r = mt * 16 + l15;
        half4 hv;
#pragma unroll
        for (int i = 0; i < 4; ++i) hv[i] = (f16)(accL[mt][i] + ((const float*)&bias)[i]);
        *(half4*)(lds + L1_OFF + r * 32 + c0 * 2) = hv;
      }
    }
  }
  __syncthreads();  // b4

  // ---- GEMM3: L2 = h2 @ W22 ; c2 softmax fully in-lane (lanes 0-15) -> C2 ----
  {
    floatx4 acc3 = (floatx4){0.f, 0.f, 0.f, 0.f};
    int r = w * 16 + l15;
#pragma unroll
    for (int kt = 0; kt < 4; ++kt) {
      int addr = (r * 512 + kt * 64 + (l4 << 4)) ^ ((r & 7) << 4);
      half8 Bh2 = *(const half8*)(lds + addr);
      half8 Wf = *(const half8*)(wsh + WC_OFF + (size_t)(kt * 64 + lane) * 8);
      acc3 = MFMA16(Wf, Bh2, acc3);
    }
    if (lane < 16) {
      float4 bias = *(const float4*)(wsf + BCC_OFF);
      float q0 = acc3[0] + bias.x, q1 = acc3[1] + bias.y;
      float q2 = acc3[2] + bias.z, q3 = acc3[3] + bias.w;
      float m2 = fmaxf(fmaxf(q0, q1), fmaxf(q2, q3));
      float f0 = __expf(q0 - m2), f1 = __expf(q1 - m2);
      float f2 = __expf(q2 - m2), f3 = __expf(q3 - m2);
      float inv2 = 1.f / (f0 + f1 + f2 + f3);
      float4 c2o;
      c2o.x = f0 * inv2; c2o.y = f1 * inv2; c2o.z = f2 * inv2; c2o.w = f3 * inv2;
      *(float4*)(lds + C2_OFF + r * 16) = c2o;
    }
  }

  // ---- c1 softmax + in2 mix into regs (no dep on GEMM3; same barrier interval) ----
  {
    int r = t >> 2, f = t & 3;
    const f16* L1p = (const f16*)(lds + L1_OFF) + r * 16 + f;
    float a0 = (float)L1p[0], a1 = (float)L1p[4], a2 = (float)L1p[8], a3 = (float)L1p[12];
    float m = fmaxf(fmaxf(a0, a1), fmaxf(a2, a3));
    float e0 = __expf(a0 - m), e1 = __expf(a1 - m), e2 = __expf(a2 - m), e3 = __expf(a3 - m);
    float inv = 1.f / (e0 + e1 + e2 + e3);
    float c0v = e0 * inv, c1v = e1 * inv, c2v = e2 * inv, c3v = e3 * inv;
    int sw = (r & 7) << 4;
    half8 res[4];
#pragma unroll
    for (int h8 = 0; h8 < 4; ++h8) {
      half8 o0 = *(const half8*)(lds + ((r * 512 + 256 + 0   + h8 * 16) ^ sw));
      half8 o1v = *(const half8*)(lds + ((r * 512 + 256 + 64  + h8 * 16) ^ sw));
      half8 o2v = *(const half8*)(lds + ((r * 512 + 256 + 128 + h8 * 16) ^ sw));
      half8 o3v = *(const half8*)(lds + ((r * 512 + 256 + 192 + h8 * 16) ^ sw));
      half8 rr;
#pragma unroll
      for (int j = 0; j < 8; ++j) {
        float v = c0v * (float)o0[j] + c1v * (float)o1v[j] + c2v * (float)o2v[j] + c3v * (float)o3v[j];
        rr[j] = (f16)v;
      }
      res[h8] = rr;
    }
    __syncthreads();  // b5: all o1 reads done before in-place in2 overwrite
#pragma unroll
    for (int h8 = 0; h8 < 4; ++h8)
      *(half8*)(lds + ((r * 512 + 256 + f * 64 + h8 * 16) ^ sw)) = res[h8];
  }
  __syncthreads();  // b6

  // ---- GEMM4 (wave w = expert e) + fused Wfin reduce ----
  {
    floatx4 acc4[2][4];
#pragma unroll
    for (int ct = 0; ct < 2; ++ct)
#pragma unroll
      for (int mt = 0; mt < 4; ++mt) acc4[ct][mt] = (floatx4){0.f, 0.f, 0.f, 0.f};
    half8 Bi[4];
#pragma unroll
    for (int mt = 0; mt < 4; ++mt) {
      int r = mt * 16 + l15;
      int addr = (r * 512 + 256 + w * 64 + (l4 << 4)) ^ ((r & 7) << 4);
      Bi[mt] = *(const half8*)(lds + addr);
    }
#pragma unroll
    for (int ct = 0; ct < 2; ++ct) {
      half8 Wf = *(const half8*)(wsh + WF2_OFF + (size_t)((w * 2 + ct) * 64 + lane) * 8);
#pragma unroll
      for (int mt = 0; mt < 4; ++mt) acc4[ct][mt] = MFMA16(Wf, Bi[mt], acc4[ct][mt]);
    }
    float4 bias0 = *(const float4*)(wsf + BF2_OFF + w * 32 + l4 * 4);
    float4 bias1 = *(const float4*)(wsf + BF2_OFF + w * 32 + 16 + l4 * 4);
    float4 wf0 = *(const float4*)(wsf + WFIN_OFF + l4 * 4);
    float4 wf1 = *(const float4*)(wsf + WFIN_OFF + 16 + l4 * 4);
#pragma unroll
    for (int mt = 0; mt < 4; ++mt) {
      int r = mt * 16 + l15;
      float s = 0.f;
#pragma unroll
      for (int i = 0; i < 4; ++i) {
        s += fmaxf(acc4[0][mt][i] + ((const float*)&bias0)[i], 0.f) * ((const float*)&wf0)[i];
        s += fmaxf(acc4[1][mt][i] + ((const float*)&bias1)[i], 0.f) * ((const float*)&wf1)[i];
      }
      s += __shfl_xor(s, 16);
      s += __shfl_xor(s, 32);
      if (l4 == 0) {
        float c2e = *(const float*)(lds + C2_OFF + r * 16 + w * 4);
        *(float*)(lds + PART_OFF + (w * 64 + r) * 4) = s * c2e;
      }
    }
  }
  __syncthreads();  // b7

  if (t < 64) {
    float s = wsf[BFIN_OFF];
#pragma unroll
    for (int e = 0; e < 4; ++e) s += *(const float*)(lds + PART_OFF + e * 256 + t * 4);
    out[base + t] = s;
  }
}

extern "C" void kernel_launch(void* const* d_in, const int* in_sizes, int n_in,
                              void* d_out, int out_size, void* d_ws, size_t ws_size,
                              hipStream_t stream) {
  (void)in_sizes; (void)n_in; (void)ws_size;
  const float* x    = (const float*)d_in[0];
  const float* ctx  = (const float*)d_in[1];
  const float* W1   = (const float*)d_in[2];
  const float* b1   = (const float*)d_in[3];
  const float* W2   = (const float*)d_in[4];
  const float* b2   = (const float*)d_in[5];
  const float* W12  = (const float*)d_in[6];
  const float* b12  = (const float*)d_in[7];
  const float* W22  = (const float*)d_in[8];
  const float* b22  = (const float*)d_in[9];
  const float* Wf1  = (const float*)d_in[10];
  const float* bf1  = (const float*)d_in[11];
  const float* Wf2  = (const float*)d_in[12];
  const float* bf2  = (const float*)d_in[13];
  const float* Wfin = (const float*)d_in[14];
  const float* bfin = (const float*)d_in[15];

  f16* wsh = (f16*)d_ws;
  float* wsf = (float*)((char*)d_ws + WSF_BYTE_OFF);

  prep_kernel<<<355, 256, 0, stream>>>(ctx, W1, b1, W2, b2, W12, b12, W22, b22,
                                       Wf1, bf1, Wf2, bf2, Wfin, bfin, wsh, wsf);

  int nblocks = 262144 / BM;  // 4096
  fused_kernel<<<nblocks, 256, 0, stream>>>(x, wsh, wsf, (float*)d_out);
}

// Round 4
// 112.945 us; speedup vs baseline: 1.0173x; 1.0173x over previous
//
#include <hip/hip_runtime.h>
#include <hip/hip_bf16.h>

typedef _Float16 f16;
typedef _Float16 half8 __attribute__((ext_vector_type(8)));
typedef _Float16 half4 __attribute__((ext_vector_type(4)));
typedef float floatx4 __attribute__((ext_vector_type(4)));

#define BM 64

// ---- ws layout (f16 element offsets) ----
#define WA_OFF 0         // 65536 f16 : WaT frag order (CT=16,KT=8) — A-operand of swapped GEMM1
#define WB_OFF 65536     // 18432 f16 : WbT (CT=9, KT=4)  ct: 0-7=W2, 8=W12
#define WC_OFF 83968     // 2048 f16  : WcT (CT=1, KT=4)  rows 0-3 = W22 cols
#define WF2_OFF 86016    // 4096 f16  : Wf2T [4][CT=2,KT=1]
#define WSF_BYTE_OFF 180224
// wsf (float offsets)
#define BA_OFF 0      // 256: b1 | bf1
#define BB_OFF 256    // 144: b2 | b12
#define BCC_OFF 400   // 4  : b22
#define BF2_OFF 404   // 128: bf2
#define WFIN_OFF 532  // 32
#define BFIN_OFF 564  // 1

__global__ __launch_bounds__(256) void prep_kernel(
    const float* __restrict__ ctx, const float* __restrict__ W1,
    const float* __restrict__ b1, const float* __restrict__ W2,
    const float* __restrict__ b2, const float* __restrict__ W12,
    const float* __restrict__ b12, const float* __restrict__ W22,
    const float* __restrict__ b22, const float* __restrict__ Wf1,
    const float* __restrict__ bf1, const float* __restrict__ Wf2,
    const float* __restrict__ bf2, const float* __restrict__ Wfin,
    const float* __restrict__ bfin, f16* __restrict__ wsh,
    float* __restrict__ wsf)
{
  int tid = blockIdx.x * 256 + threadIdx.x;
  if (tid < 65536) {
    int j = tid & 7, l = (tid >> 3) & 63, kt = (tid >> 9) & 7, nt = tid >> 12;
    int k = kt * 32 + ((l >> 4) << 3) + j, n = nt * 16 + (l & 15);
    float v;
    if (n < 128) v = ctx[k] * W1[k * 128 + n];
    else { int c = n - 128; v = Wf1[((c >> 5) * 256 + k) * 32 + (c & 31)]; }
    wsh[tid] = (f16)v;
  } else if (tid < WB_OFF + 18432) {
    int o = tid - WB_OFF;
    int j = o & 7, l = (o >> 3) & 63, kt = (o >> 9) & 3, nt = o >> 11;
    int k = kt * 32 + ((l >> 4) << 3) + j, n = nt * 16 + (l & 15);
    float v = (n < 128) ? W2[k * 128 + n] : W12[k * 16 + (n - 128)];
    wsh[tid] = (f16)v;
  } else if (tid < WC_OFF + 2048) {
    int o = tid - WC_OFF;
    int j = o & 7, l = (o >> 3) & 63, kt = (o >> 9) & 3;
    int k = kt * 32 + ((l >> 4) << 3) + j, n = l & 15;
    float v = (n < 4) ? W22[k * 4 + n] : 0.f;
    wsh[tid] = (f16)v;
  } else if (tid < WF2_OFF + 4096) {
    int o = tid - WF2_OFF;
    int j = o & 7, l = (o >> 3) & 63, ent = o >> 9;
    int e = ent >> 1, nt = ent & 1;
    int k = ((l >> 4) << 3) + j, n = nt * 16 + (l & 15);
    wsh[tid] = (f16)Wf2[(e * 32 + k) * 32 + n];
  } else if (tid < 90112 + 565) {
    int o = tid - 90112;
    float v;
    if (o < 128) v = b1[o];
    else if (o < 256) v = bf1[o - 128];
    else if (o < 384) v = b2[o - 256];
    else if (o < 400) v = b12[o - 384];
    else if (o < 404) v = b22[o - 400];
    else if (o < 532) v = bf2[o - 404];
    else if (o < 564) v = Wfin[o - 532];
    else v = bfin[0];
    wsf[o] = v;
  }
}

#define MFMA16(A, Bv, C) __builtin_amdgcn_mfma_f32_16x16x32_f16(A, Bv, C, 0, 0, 0)

// LDS map (bytes), 35 KB total -> 4 blocks/CU (LDS-limited):
//  G    0..32767   [64][512B] f16 swz :
//        phase A: x-tile ([64][256] f16)
//        phase B: h (bytes 0..255/row) | o1 (bytes 256..511/row)
//        phase C: h2 overlays h in place; in2 overlays o1 in place
//  L1   32768..34815 [64][16] f16 : logits1 ; overlaid by part [4][64] f32 in G4
//  C2   34816..35839 [64][4] f32
#define L1_OFF 32768
#define PART_OFF 32768
#define C2_OFF 34816

// NOTE: 2nd arg = 3 (NOT 4): hipcc caps VGPR at ~256/w; w=4 forced 64 VGPR
// and ~15 f32/thread scratch spill (R3: WRITE_SIZE 1MB->62MB). At w=3 the
// compiler lands ~80 VGPR; HW pool is 512/SIMD so 80 VGPR still permits
// >=4 waves/SIMD -> occupancy stays LDS-limited at 4 blocks/CU.
__global__ __launch_bounds__(256, 3) void fused_kernel(
    const float* __restrict__ x, const f16* __restrict__ wsh,
    const float* __restrict__ wsf, float* __restrict__ out)
{
  __shared__ __attribute__((aligned(16))) char lds[35840];
  const int t = threadIdx.x;
  const int lane = t & 63;
  const int w = t >> 6;
  const int l15 = lane & 15;
  const int l4 = lane >> 4;
  const size_t base = (size_t)blockIdx.x * BM;

  // ---- stage x tile -> G (f16, swizzled) ----
#pragma unroll
  for (int it = 0; it < 8; ++it) {
    int c = it * 256 + t;
    int r = c >> 5;
    int k0 = (c & 31) << 3;
    const float4* xv = (const float4*)(x + (base + (size_t)r) * 256 + k0);
    float4 a = xv[0], b = xv[1];
    half8 hv;
    hv[0] = (f16)a.x; hv[1] = (f16)a.y; hv[2] = (f16)a.z; hv[3] = (f16)a.w;
    hv[4] = (f16)b.x; hv[5] = (f16)b.y; hv[6] = (f16)b.z; hv[7] = (f16)b.w;
    int addr = (r * 512 + k0 * 2) ^ ((r & 7) << 4);
    *(half8*)(lds + addr) = hv;
  }
  __syncthreads();  // b0

  // ---- GEMM1 (swapped: A=WaT, B=x): h|o1 = relu(...), overlaying x ----
  {
    floatx4 acc[4][4];
#pragma unroll
    for (int q = 0; q < 4; ++q)
#pragma unroll
      for (int mt = 0; mt < 4; ++mt) acc[q][mt] = (floatx4){0.f, 0.f, 0.f, 0.f};
    for (int kt = 0; kt < 8; ++kt) {
      half8 Bx[4];
#pragma unroll
      for (int mt = 0; mt < 4; ++mt) {
        int r = mt * 16 + l15;
        int addr = (r * 512 + kt * 64 + (l4 << 4)) ^ ((r & 7) << 4);
        Bx[mt] = *(const half8*)(lds + addr);
      }
#pragma unroll
      for (int q = 0; q < 4; ++q) {
        half8 Wf = *(const half8*)(wsh + WA_OFF + (size_t)(((w * 4 + q) * 8 + kt) * 64 + lane) * 8);
#pragma unroll
        for (int mt = 0; mt < 4; ++mt) acc[q][mt] = MFMA16(Wf, Bx[mt], acc[q][mt]);
      }
    }
    __syncthreads();  // b1: all x reads done before overlay writes
#pragma unroll
    for (int q = 0; q < 4; ++q) {
      int c0 = (w * 4 + q) * 16 + l4 * 4;
      float4 bias = *(const float4*)(wsf + BA_OFF + c0);
#pragma unroll
      for (int mt = 0; mt < 4; ++mt) {
        int r = mt * 16 + l15;
        half4 hv;
#pragma unroll
        for (int i = 0; i < 4; ++i) hv[i] = (f16)fmaxf(acc[q][mt][i] + ((const float*)&bias)[i], 0.f);
        int addr = (r * 512 + c0 * 2) ^ ((r & 7) << 4);
        *(half4*)(lds + addr) = hv;
      }
    }
  }
  __syncthreads();  // b2

  // ---- GEMM2: h2 = relu(h @ W2) overlaying h; L1 = h @ W12 ----
  {
    floatx4 acc2[2][4];
    floatx4 accL[4];
#pragma unroll
    for (int qi = 0; qi < 2; ++qi)
#pragma unroll
      for (int mt = 0; mt < 4; ++mt) acc2[qi][mt] = (floatx4){0.f, 0.f, 0.f, 0.f};
#pragma unroll
    for (int mt = 0; mt < 4; ++mt) accL[mt] = (floatx4){0.f, 0.f, 0.f, 0.f};

    for (int kt = 0; kt < 4; ++kt) {
      half8 Bh[4];
#pragma unroll
      for (int mt = 0; mt < 4; ++mt) {
        int r = mt * 16 + l15;
        int addr = (r * 512 + kt * 64 + (l4 << 4)) ^ ((r & 7) << 4);
        Bh[mt] = *(const half8*)(lds + addr);
      }
#pragma unroll
      for (int qi = 0; qi < 2; ++qi) {
        half8 Wf = *(const half8*)(wsh + WB_OFF + (size_t)(((w + qi * 4) * 4 + kt) * 64 + lane) * 8);
#pragma unroll
        for (int mt = 0; mt < 4; ++mt) acc2[qi][mt] = MFMA16(Wf, Bh[mt], acc2[qi][mt]);
      }
      if (w == 3) {
        half8 Wf = *(const half8*)(wsh + WB_OFF + (size_t)((32 + kt) * 64 + lane) * 8);
#pragma unroll
        for (int mt = 0; mt < 4; ++mt) accL[mt] = MFMA16(Wf, Bh[mt], accL[mt]);
      }
    }
    __syncthreads();  // b3: all h reads done before in-place h2 overwrite
#pragma unroll
    for (int qi = 0; qi < 2; ++qi) {
      int c0 = (w + qi * 4) * 16 + l4 * 4;
      float4 bias = *(const float4*)(wsf + BB_OFF + c0);
#pragma unroll
      for (int mt = 0; mt < 4; ++mt) {
        int r = mt * 16 + l15;
        half4 hv;
#pragma unroll
        for (int i = 0; i < 4; ++i) hv[i] = (f16)fmaxf(acc2[qi][mt][i] + ((const float*)&bias)[i], 0.f);
        int addr = (r * 512 + c0 * 2) ^ ((r & 7) << 4);
        *(half4*)(lds + addr) = hv;
      }
    }
    if (w == 3) {
      int c0 = l4 * 4;
      float4 bias = *(const float4*)(wsf + BB_OFF + 128 + c0);
#pragma unroll
      for (int mt = 0; mt < 4; ++mt) {
        int r = mt * 16 + l15;
        half4 hv;
#pragma unroll
        for (int i = 0; i < 4; ++i) hv[i] = (f16)(accL[mt][i] + ((const float*)&bias)[i]);
        *(half4*)(lds + L1_OFF + r * 32 + c0 * 2) = hv;
      }
    }
  }
  __syncthreads();  // b4

  // ---- GEMM3: L2 = h2 @ W22 ; c2 softmax fully in-lane (lanes 0-15) -> C2 ----
  {
    floatx4 acc3 = (floatx4){0.f, 0.f, 0.f, 0.f};
    int r = w * 16 + l15;
#pragma unroll
    for (int kt = 0; kt < 4; ++kt) {
      int addr = (r * 512 + kt * 64 + (l4 << 4)) ^ ((r & 7) << 4);
      half8 Bh2 = *(const half8*)(lds + addr);
      half8 Wf = *(const half8*)(wsh + WC_OFF + (size_t)(kt * 64 + lane) * 8);
      acc3 = MFMA16(Wf, Bh2, acc3);
    }
    if (lane < 16) {
      float4 bias = *(const float4*)(wsf + BCC_OFF);
      float q0 = acc3[0] + bias.x, q1 = acc3[1] + bias.y;
      float q2 = acc3[2] + bias.z, q3 = acc3[3] + bias.w;
      float m2 = fmaxf(fmaxf(q0, q1), fmaxf(q2, q3));
      float f0 = __expf(q0 - m2), f1 = __expf(q1 - m2);
      float f2 = __expf(q2 - m2), f3 = __expf(q3 - m2);
      float inv2 = 1.f / (f0 + f1 + f2 + f3);
      float4 c2o;
      c2o.x = f0 * inv2; c2o.y = f1 * inv2; c2o.z = f2 * inv2; c2o.w = f3 * inv2;
      *(float4*)(lds + C2_OFF + r * 16) = c2o;
    }
  }

  // ---- c1 softmax + in2 mix into regs (no dep on GEMM3; same barrier interval) ----
  {
    int r = t >> 2, f = t & 3;
    const f16* L1p = (const f16*)(lds + L1_OFF) + r * 16 + f;
    float a0 = (float)L1p[0], a1 = (float)L1p[4], a2 = (float)L1p[8], a3 = (float)L1p[12];
    float m = fmaxf(fmaxf(a0, a1), fmaxf(a2, a3));
    float e0 = __expf(a0 - m), e1 = __expf(a1 - m), e2 = __expf(a2 - m), e3 = __expf(a3 - m);
    float inv = 1.f / (e0 + e1 + e2 + e3);
    float c0v = e0 * inv, c1v = e1 * inv, c2v = e2 * inv, c3v = e3 * inv;
    int sw = (r & 7) << 4;
    half8 res[4];
#pragma unroll
    for (int h8 = 0; h8 < 4; ++h8) {
      half8 o0 = *(const half8*)(lds + ((r * 512 + 256 + 0   + h8 * 16) ^ sw));
      half8 o1v = *(const half8*)(lds + ((r * 512 + 256 + 64  + h8 * 16) ^ sw));
      half8 o2v = *(const half8*)(lds + ((r * 512 + 256 + 128 + h8 * 16) ^ sw));
      half8 o3v = *(const half8*)(lds + ((r * 512 + 256 + 192 + h8 * 16) ^ sw));
      half8 rr;
#pragma unroll
      for (int j = 0; j < 8; ++j) {
        float v = c0v * (float)o0[j] + c1v * (float)o1v[j] + c2v * (float)o2v[j] + c3v * (float)o3v[j];
        rr[j] = (f16)v;
      }
      res[h8] = rr;
    }
    __syncthreads();  // b5: all o1 reads done before in-place in2 overwrite
#pragma unroll
    for (int h8 = 0; h8 < 4; ++h8)
      *(half8*)(lds + ((r * 512 + 256 + f * 64 + h8 * 16) ^ sw)) = res[h8];
  }
  __syncthreads();  // b6

  // ---- GEMM4 (wave w = expert e) + fused Wfin reduce ----
  {
    floatx4 acc4[2][4];
#pragma unroll
    for (int ct = 0; ct < 2; ++ct)
#pragma unroll
      for (int mt = 0; mt < 4; ++mt) acc4[ct][mt] = (floatx4){0.f, 0.f, 0.f, 0.f};
    half8 Bi[4];
#pragma unroll
    for (int mt = 0; mt < 4; ++mt) {
      int r = mt * 16 + l15;
      int addr = (r * 512 + 256 + w * 64 + (l4 << 4)) ^ ((r & 7) << 4);
      Bi[mt] = *(const half8*)(lds + addr);
    }
#pragma unroll
    for (int ct = 0; ct < 2; ++ct) {
      half8 Wf = *(const half8*)(wsh + WF2_OFF + (size_t)((w * 2 + ct) * 64 + lane) * 8);
#pragma unroll
      for (int mt = 0; mt < 4; ++mt) acc4[ct][mt] = MFMA16(Wf, Bi[mt], acc4[ct][mt]);
    }
    float4 bias0 = *(const float4*)(wsf + BF2_OFF + w * 32 + l4 * 4);
    float4 bias1 = *(const float4*)(wsf + BF2_OFF + w * 32 + 16 + l4 * 4);
    float4 wf0 = *(const float4*)(wsf + WFIN_OFF + l4 * 4);
    float4 wf1 = *(const float4*)(wsf + WFIN_OFF + 16 + l4 * 4);
#pragma unroll
    for (int mt = 0; mt < 4; ++mt) {
      int r = mt * 16 + l15;
      float s = 0.f;
#pragma unroll
      for (int i = 0; i < 4; ++i) {
        s += fmaxf(acc4[0][mt][i] + ((const float*)&bias0)[i], 0.f) * ((const float*)&wf0)[i];
        s += fmaxf(acc4[1][mt][i] + ((const float*)&bias1)[i], 0.f) * ((const float*)&wf1)[i];
      }
      s += __shfl_xor(s, 16);
      s += __shfl_xor(s, 32);
      if (l4 == 0) {
        float c2e = *(const float*)(lds + C2_OFF + r * 16 + w * 4);
        *(float*)(lds + PART_OFF + (w * 64 + r) * 4) = s * c2e;
      }
    }
  }
  __syncthreads();  // b7

  if (t < 64) {
    float s = wsf[BFIN_OFF];
#pragma unroll
    for (int e = 0; e < 4; ++e) s += *(const float*)(lds + PART_OFF + e * 256 + t * 4);
    out[base + t] = s;
  }
}

extern "C" void kernel_launch(void* const* d_in, const int* in_sizes, int n_in,
                              void* d_out, int out_size, void* d_ws, size_t ws_size,
                              hipStream_t stream) {
  (void)in_sizes; (void)n_in; (void)ws_size;
  const float* x    = (const float*)d_in[0];
  const float* ctx  = (const float*)d_in[1];
  const float* W1   = (const float*)d_in[2];
  const float* b1   = (const float*)d_in[3];
  const float* W2   = (const float*)d_in[4];
  const float* b2   = (const float*)d_in[5];
  const float* W12  = (const float*)d_in[6];
  const float* b12  = (const float*)d_in[7];
  const float* W22  = (const float*)d_in[8];
  const float* b22  = (const float*)d_in[9];
  const float* Wf1  = (const float*)d_in[10];
  const float* bf1  = (const float*)d_in[11];
  const float* Wf2  = (const float*)d_in[12];
  const float* bf2  = (const float*)d_in[13];
  const float* Wfin = (const float*)d_in[14];
  const float* bfin = (const float*)d_in[15];

  f16* wsh = (f16*)d_ws;
  float* wsf = (float*)((char*)d_ws + WSF_BYTE_OFF);

  prep_kernel<<<355, 256, 0, stream>>>(ctx, W1, b1, W2, b2, W12, b12, W22, b22,
                                       Wf1, bf1, Wf2, bf2, Wfin, bfin, wsh, wsf);

  int nblocks = 262144 / BM;  // 4096
  fused_kernel<<<nblocks, 256, 0, stream>>>(x, wsh, wsf, (float*)d_out);
}